// Round 2
// baseline (1665.635 us; speedup 1.0000x reference)
//
#include <hip/hip_runtime.h>

#define NB    2
#define NCAM  6
#define FD    256
#define KK    1680
#define DIMN  128
#define NHEAD 4
#define DHD   32
#define QQ    2500
#define SCALE 0.17677669529663687f

// ---------- helpers ----------
__device__ __forceinline__ float blk_sum128(float v, float* red) {
  #pragma unroll
  for (int o = 32; o > 0; o >>= 1) v += __shfl_down(v, o);
  int t = threadIdx.x;
  if ((t & 63) == 0) red[t >> 6] = v;
  __syncthreads();
  float r = red[0] + red[1];
  __syncthreads();
  return r;
}

// ---------- K1: camera-center embedding ----------
__global__ void k_cembed(const float* __restrict__ W_cam, const float* __restrict__ E_inv,
                         float* __restrict__ ce) {
  int bn = blockIdx.x;         // 0..11
  int d  = threadIdx.x;        // 0..127
  const float* e = E_inv + bn * 16;
  float s = 0.f;
  #pragma unroll
  for (int c = 0; c < 4; ++c) s += W_cam[d * 4 + c] * e[c * 4 + 3];
  ce[bn * 128 + d] = s;
}

// ---------- K2: per-pixel ray embedding (normalized) -> key buffer ----------
__global__ void k_img(const float* __restrict__ I_inv, const float* __restrict__ E_inv,
                      const float* __restrict__ plane, const float* __restrict__ W_img,
                      const float* __restrict__ ce, float* __restrict__ key) {
  __shared__ float red[2];
  int p  = blockIdx.x;         // 0..1679
  int bn = blockIdx.y;         // 0..11
  int d  = threadIdx.x;
  const float* Ii = I_inv + bn * 9;
  const float* Ei = E_inv + bn * 16;
  float pl0 = plane[p], pl1 = plane[KK + p], pl2 = plane[2 * KK + p];
  float c0 = Ii[0]*pl0 + Ii[1]*pl1 + Ii[2]*pl2;
  float c1 = Ii[3]*pl0 + Ii[4]*pl1 + Ii[5]*pl2;
  float c2 = Ii[6]*pl0 + Ii[7]*pl1 + Ii[8]*pl2;
  float d0 = Ei[0]*c0 + Ei[1]*c1 + Ei[2]*c2  + Ei[3];
  float d1 = Ei[4]*c0 + Ei[5]*c1 + Ei[6]*c2  + Ei[7];
  float d2 = Ei[8]*c0 + Ei[9]*c1 + Ei[10]*c2 + Ei[11];
  float d3 = Ei[12]*c0 + Ei[13]*c1 + Ei[14]*c2 + Ei[15];
  float v = W_img[d*4]*d0 + W_img[d*4+1]*d1 + W_img[d*4+2]*d2 + W_img[d*4+3]*d3
            - ce[bn * 128 + d];
  float ss = blk_sum128(v * v, red);
  float inv = 1.f / (sqrtf(ss) + 1e-7f);
  key[((size_t)bn * KK + p) * DIMN + d] = v * inv;
}

// ---------- K3: BEV positional embedding + x -> query buffer ----------
__global__ void k_query(const float* __restrict__ bev_grid, const float* __restrict__ W_bev,
                        const float* __restrict__ b_bev, const float* __restrict__ ce,
                        const float* __restrict__ x, float* __restrict__ query) {
  __shared__ float red[2];
  int q  = blockIdx.x;         // 0..2499
  int bn = blockIdx.y;         // 0..11
  int b  = bn / NCAM;
  int d  = threadIdx.x;
  float g0 = bev_grid[q], g1 = bev_grid[QQ + q];
  float v = W_bev[d * 2] * g0 + W_bev[d * 2 + 1] * g1 + b_bev[d] - ce[bn * 128 + d];
  float ss = blk_sum128(v * v, red);
  float inv = 1.f / (sqrtf(ss) + 1e-7f);
  query[((size_t)bn * QQ + q) * DIMN + d] = v * inv + x[(size_t)(b * DIMN + d) * QQ + q];
}

// ---------- K4: BN+ReLU + dual 1x1 conv on feature; key += fproj, val = flin ----------
#define TP 16
__global__ void k_featconv(const float* __restrict__ feat,
                           const float* __restrict__ g1c, const float* __restrict__ b1c,
                           const float* __restrict__ m1c, const float* __restrict__ v1c,
                           const float* __restrict__ g2c, const float* __restrict__ b2c,
                           const float* __restrict__ m2c, const float* __restrict__ v2c,
                           const float* __restrict__ Wfp, const float* __restrict__ Wfl,
                           float* __restrict__ key, float* __restrict__ val) {
  __shared__ float sc1[FD], sh1[FD], sc2[FD], sh2[FD];
  __shared__ float t1[FD * (TP + 1)];
  __shared__ float t2[FD * (TP + 1)];
  int tile = blockIdx.x;       // 0..104
  int bn   = blockIdx.y;       // 0..11
  int t    = threadIdx.x;      // 0..255
  int p0   = tile * TP;
  {
    int c = t;
    float s1 = g1c[c] * rsqrtf(v1c[c] + 1e-5f);
    sc1[c] = s1; sh1[c] = b1c[c] - m1c[c] * s1;
    float s2 = g2c[c] * rsqrtf(v2c[c] + 1e-5f);
    sc2[c] = s2; sh2[c] = b2c[c] - m2c[c] * s2;
  }
  __syncthreads();
  // stage raw tile with BN+ReLU applied (both variants)
  const float* fb = feat + (size_t)bn * FD * KK + p0;
  int pp = t & 15, crow = t >> 4;
  #pragma unroll
  for (int i = 0; i < 16; ++i) {
    int c = i * 16 + crow;
    float raw = fb[(size_t)c * KK + pp];
    t1[c * (TP + 1) + pp] = fmaxf(raw * sc1[c] + sh1[c], 0.f);
    t2[c * (TP + 1) + pp] = fmaxf(raw * sc2[c] + sh2[c], 0.f);
  }
  __syncthreads();
  // conv: threads 0..127 -> fproj (dd=t), threads 128..255 -> flin
  int dd = t & 127;
  const float4* W4 = (const float4*)((t < 128) ? Wfp : Wfl) + dd * 64;
  const float* tl = (t < 128) ? t1 : t2;
  float acc[TP];
  #pragma unroll
  for (int p = 0; p < TP; ++p) acc[p] = 0.f;
  for (int c4 = 0; c4 < 64; ++c4) {
    float4 w = W4[c4];
    const float* r0 = &tl[(c4 * 4 + 0) * (TP + 1)];
    const float* r1 = &tl[(c4 * 4 + 1) * (TP + 1)];
    const float* r2 = &tl[(c4 * 4 + 2) * (TP + 1)];
    const float* r3 = &tl[(c4 * 4 + 3) * (TP + 1)];
    #pragma unroll
    for (int p = 0; p < TP; ++p)
      acc[p] += w.x * r0[p] + w.y * r1[p] + w.z * r2[p] + w.w * r3[p];
  }
  __syncthreads();
  {   // write results transposed into LDS (reuse t1/t2)
    float* dst = (t < 128) ? t1 : t2;
    #pragma unroll
    for (int p = 0; p < TP; ++p) dst[dd * (TP + 1) + p] = acc[p];
  }
  __syncthreads();
  // coalesced store: e = i*256 + t -> dd = e&127, p = (e>>7)&15, which = e>>11
  #pragma unroll
  for (int i = 0; i < 16; ++i) {
    int e   = i * 256 + t;
    int ddo = e & 127, po = (e >> 7) & 15, wh = e >> 11;
    size_t addr = ((size_t)bn * KK + p0 + po) * DIMN + ddo;
    float vv = (wh ? t2 : t1)[ddo * (TP + 1) + po];
    if (wh) val[addr] = vv;
    else    key[addr] += vv;
  }
}

// ---------- K5: LayerNorm + 128x128 projection (8 rows / block) ----------
#define ROWS 8
__global__ void k_lnproj(const float* __restrict__ in, const float* __restrict__ lng,
                         const float* __restrict__ lnb, const float* __restrict__ W,
                         const float* __restrict__ bias, float* __restrict__ out) {
  __shared__ float red[2];
  __shared__ float ln[ROWS][DIMN];
  __shared__ float stats[ROWS][2];
  size_t r0 = (size_t)blockIdx.x * ROWS;
  int t = threadIdx.x;
  float g = lng[t], bb = lnb[t];
  float xv[ROWS];
  #pragma unroll
  for (int r = 0; r < ROWS; ++r) xv[r] = in[(r0 + r) * DIMN + t];
  #pragma unroll
  for (int r = 0; r < ROWS; ++r) {
    float s  = blk_sum128(xv[r], red);
    float s2 = blk_sum128(xv[r] * xv[r], red);
    if (t == 0) { stats[r][0] = s * (1.f / 128.f); stats[r][1] = s2 * (1.f / 128.f); }
  }
  __syncthreads();
  #pragma unroll
  for (int r = 0; r < ROWS; ++r) {
    float mu  = stats[r][0];
    float var = fmaxf(stats[r][1] - mu * mu, 0.f);
    float rin = rsqrtf(var + 1e-5f);
    ln[r][t] = (xv[r] - mu) * rin * g + bb;
  }
  __syncthreads();
  float acc[ROWS];
  float bv = bias[t];
  #pragma unroll
  for (int r = 0; r < ROWS; ++r) acc[r] = bv;
  const float4* W4 = (const float4*)W + t * 32;
  for (int j4 = 0; j4 < 32; ++j4) {
    float4 w = W4[j4];
    #pragma unroll
    for (int r = 0; r < ROWS; ++r)
      acc[r] += w.x * ln[r][j4*4] + w.y * ln[r][j4*4+1] + w.z * ln[r][j4*4+2] + w.w * ln[r][j4*4+3];
  }
  #pragma unroll
  for (int r = 0; r < ROWS; ++r) out[(r0 + r) * DIMN + t] = acc[r];
}

// ---------- K6: flash-style cross attention ----------
// grid (157, 4, 2); block 256. 16 queries per block; online softmax over 6*1680 keys.
#define QT 16
__global__ __launch_bounds__(256, 4)
void k_attn(const float* __restrict__ qh, const float* __restrict__ kh,
            const float* __restrict__ vh, float* __restrict__ aout) {
  __shared__ float qv [96 * 36];   // [n*16+qi][36] q fragments
  __shared__ float khl[64 * 36];   // [k][36]
  __shared__ float vhl[32 * 68];   // transposed: [d][68]
  __shared__ float pls[16 * 68];   // [qi][68]
  __shared__ float red[16 * 17];
  __shared__ float m_run[16], l_run[16], alpha_s[16], mnew_s[16];
  int qt = blockIdx.x, m = blockIdx.y, b = blockIdx.z;
  int q0 = qt * QT;
  int t  = threadIdx.x;
  int qi = t & 15, g = t >> 4;
  for (int e = t; e < 768; e += 256) {
    int d4 = e & 7, qq = (e >> 3) & 15, n = e >> 7;
    int q = q0 + qq;
    float4 v = make_float4(0.f, 0.f, 0.f, 0.f);
    if (q < QQ) v = *(const float4*)&qh[((size_t)(b * NCAM + n) * QQ + q) * DIMN + m * DHD + d4 * 4];
    float* dst = &qv[(n * 16 + qq) * 36 + d4 * 4];
    dst[0] = v.x; dst[1] = v.y; dst[2] = v.z; dst[3] = v.w;
  }
  if (t < 16) { m_run[t] = -1e30f; l_run[t] = 0.f; }
  float acc0 = 0.f, acc1 = 0.f;
  int d0 = g * 2;
  __syncthreads();
  for (int n = 0; n < NCAM; ++n) {
    float4 qr[8];
    {
      const float4* qp = (const float4*)&qv[(n * 16 + qi) * 36];
      #pragma unroll
      for (int i = 0; i < 8; ++i) qr[i] = qp[i];
    }
    const float* khb = kh + (size_t)(b * NCAM + n) * KK * DIMN + m * DHD;
    const float* vhb = vh + (size_t)(b * NCAM + n) * KK * DIMN + m * DHD;
    for (int k0 = 0; k0 < KK; k0 += 64) {
      #pragma unroll
      for (int i = 0; i < 2; ++i) {
        int e = i * 256 + t;
        int dq = e & 7, kl = e >> 3;
        int k = k0 + kl;
        float4 kv = make_float4(0.f,0.f,0.f,0.f), vv = make_float4(0.f,0.f,0.f,0.f);
        if (k < KK) {
          kv = *(const float4*)&khb[(size_t)k * DIMN + dq * 4];
          vv = *(const float4*)&vhb[(size_t)k * DIMN + dq * 4];
        }
        *(float4*)&khl[kl * 36 + dq * 4] = kv;
        float* vt = &vhl[(dq * 4) * 68 + kl];
        vt[0] = vv.x; vt[68] = vv.y; vt[136] = vv.z; vt[204] = vv.w;
      }
      __syncthreads();
      float sc[4];
      #pragma unroll
      for (int j = 0; j < 4; ++j) {
        int kl = g + 16 * j;
        const float4* kp = (const float4*)&khl[kl * 36];
        float a = 0.f;
        #pragma unroll
        for (int i = 0; i < 8; ++i) {
          float4 kv = kp[i];
          a += qr[i].x * kv.x + qr[i].y * kv.y + qr[i].z * kv.z + qr[i].w * kv.w;
        }
        sc[j] = (k0 + kl < KK) ? a * SCALE : -1e30f;
      }
      float lmax = fmaxf(fmaxf(sc[0], sc[1]), fmaxf(sc[2], sc[3]));
      red[g * 17 + qi] = lmax;
      __syncthreads();
      if (t < 16) {
        float tm = red[t];
        #pragma unroll
        for (int gg = 1; gg < 16; ++gg) tm = fmaxf(tm, red[gg * 17 + t]);
        float mo = m_run[t];
        float mn = fmaxf(mo, tm);
        mnew_s[t] = mn; alpha_s[t] = __expf(mo - mn); m_run[t] = mn;
      }
      __syncthreads();
      float mn = mnew_s[qi], al = alpha_s[qi];
      float lsum = 0.f;
      #pragma unroll
      for (int j = 0; j < 4; ++j) {
        float p = __expf(sc[j] - mn);
        pls[qi * 68 + g + 16 * j] = p;
        lsum += p;
      }
      red[g * 17 + qi] = lsum;
      acc0 *= al; acc1 *= al;
      __syncthreads();
      if (t < 16) {
        float ts = 0.f;
        #pragma unroll
        for (int gg = 0; gg < 16; ++gg) ts += red[gg * 17 + t];
        l_run[t] = l_run[t] * alpha_s[t] + ts;
      }
      const float*  vr0  = &vhl[d0 * 68];
      const float*  vr1  = &vhl[(d0 + 1) * 68];
      const float4* prow = (const float4*)&pls[qi * 68];
      #pragma unroll
      for (int k4 = 0; k4 < 16; ++k4) {
        float4 p4 = prow[k4];
        int k = k4 * 4;
        acc0 += p4.x * vr0[k] + p4.y * vr0[k+1] + p4.z * vr0[k+2] + p4.w * vr0[k+3];
        acc1 += p4.x * vr1[k] + p4.y * vr1[k+1] + p4.z * vr1[k+2] + p4.w * vr1[k+3];
      }
      __syncthreads();
    }
  }
  int q = q0 + qi;
  if (q < QQ) {
    float inv = 1.f / l_run[qi];
    size_t o = ((size_t)b * QQ + q) * DIMN + m * DHD + d0;
    aout[o]     = acc0 * inv;
    aout[o + 1] = acc1 * inv;
  }
}

// ---------- K7: epilogue: proj + skip + preLN + MLP(GELU) + postLN + transpose ----------
__global__ void k_epi(const float* __restrict__ a, const float* __restrict__ x,
                      const float* __restrict__ Wproj, const float* __restrict__ bproj,
                      const float* __restrict__ preg, const float* __restrict__ preb,
                      const float* __restrict__ W1, const float* __restrict__ b1,
                      const float* __restrict__ W2, const float* __restrict__ b2,
                      const float* __restrict__ postg, const float* __restrict__ postb,
                      float* __restrict__ out) {
  __shared__ float red[2];
  __shared__ float sa[DIMN];
  __shared__ float sln[DIMN];
  __shared__ float sh[2 * DIMN];
  int row = blockIdx.x;            // 0..4999
  int b = row / QQ, q = row % QQ;
  int t = threadIdx.x;
  sa[t] = a[(size_t)row * DIMN + t];
  __syncthreads();
  float z = bproj[t] + x[(size_t)(b * DIMN + t) * QQ + q];
  const float4* Wp4 = (const float4*)Wproj + t * 32;
  for (int j4 = 0; j4 < 32; ++j4) {
    float4 w = Wp4[j4];
    z += w.x * sa[j4*4] + w.y * sa[j4*4+1] + w.z * sa[j4*4+2] + w.w * sa[j4*4+3];
  }
  float mu  = blk_sum128(z, red) * (1.f / 128.f);
  float s2  = blk_sum128(z * z, red) * (1.f / 128.f);
  float var = fmaxf(s2 - mu * mu, 0.f);
  float ln1 = (z - mu) * rsqrtf(var + 1e-5f) * preg[t] + preb[t];
  sln[t] = ln1;
  __syncthreads();
  float h0 = b1[t], h1 = b1[t + 128];
  const float4* W1a = (const float4*)W1 + t * 32;
  const float4* W1b = (const float4*)W1 + (t + 128) * 32;
  for (int j4 = 0; j4 < 32; ++j4) {
    float4 wa = W1a[j4], wb = W1b[j4];
    float l0 = sln[j4*4], l1 = sln[j4*4+1], l2 = sln[j4*4+2], l3 = sln[j4*4+3];
    h0 += wa.x*l0 + wa.y*l1 + wa.z*l2 + wa.w*l3;
    h1 += wb.x*l0 + wb.y*l1 + wb.z*l2 + wb.w*l3;
  }
  h0 = 0.5f * h0 * (1.f + erff(h0 * 0.70710678118f));
  h1 = 0.5f * h1 * (1.f + erff(h1 * 0.70710678118f));
  sh[t] = h0; sh[t + 128] = h1;
  __syncthreads();
  float z2 = ln1 + b2[t];
  const float4* W24 = (const float4*)W2 + t * 64;
  for (int j4 = 0; j4 < 64; ++j4) {
    float4 w = W24[j4];
    z2 += w.x * sh[j4*4] + w.y * sh[j4*4+1] + w.z * sh[j4*4+2] + w.w * sh[j4*4+3];
  }
  mu  = blk_sum128(z2, red) * (1.f / 128.f);
  s2  = blk_sum128(z2 * z2, red) * (1.f / 128.f);
  var = fmaxf(s2 - mu * mu, 0.f);
  float o = (z2 - mu) * rsqrtf(var + 1e-5f) * postg[t] + postb[t];
  out[(size_t)(b * DIMN + t) * QQ + q] = o;
}

// ---------- launch ----------
extern "C" void kernel_launch(void* const* d_in, const int* in_sizes, int n_in,
                              void* d_out, int out_size, void* d_ws, size_t ws_size,
                              hipStream_t stream) {
  const float* x        = (const float*)d_in[0];
  const float* feature  = (const float*)d_in[1];
  const float* I_inv    = (const float*)d_in[2];
  const float* E_inv    = (const float*)d_in[3];
  const float* bev_grid = (const float*)d_in[4];
  const float* plane    = (const float*)d_in[5];
  const float* W_cam    = (const float*)d_in[6];
  const float* W_img    = (const float*)d_in[7];
  const float* W_bev    = (const float*)d_in[8];
  const float* b_bev    = (const float*)d_in[9];
  const float* fp_g = (const float*)d_in[10];
  const float* fp_b = (const float*)d_in[11];
  const float* fp_m = (const float*)d_in[12];
  const float* fp_v = (const float*)d_in[13];
  const float* fl_g = (const float*)d_in[14];
  const float* fl_b = (const float*)d_in[15];
  const float* fl_m = (const float*)d_in[16];
  const float* fl_v = (const float*)d_in[17];
  const float* W_fproj = (const float*)d_in[18];
  const float* W_flin  = (const float*)d_in[19];
  const float* q_ln_g = (const float*)d_in[20];
  const float* q_ln_b = (const float*)d_in[21];
  const float* Wq = (const float*)d_in[22];
  const float* bq = (const float*)d_in[23];
  const float* k_ln_g = (const float*)d_in[24];
  const float* k_ln_b = (const float*)d_in[25];
  const float* Wk = (const float*)d_in[26];
  const float* bk = (const float*)d_in[27];
  const float* v_ln_g = (const float*)d_in[28];
  const float* v_ln_b = (const float*)d_in[29];
  const float* Wv = (const float*)d_in[30];
  const float* bv = (const float*)d_in[31];
  const float* Wproj = (const float*)d_in[32];
  const float* bproj = (const float*)d_in[33];
  const float* pre_g = (const float*)d_in[34];
  const float* pre_b = (const float*)d_in[35];
  const float* W1 = (const float*)d_in[36];
  const float* b1 = (const float*)d_in[37];
  const float* W2 = (const float*)d_in[38];
  const float* b2 = (const float*)d_in[39];
  const float* post_g = (const float*)d_in[40];
  const float* post_b = (const float*)d_in[41];

  float* ws    = (float*)d_ws;
  float* ce    = ws;                      // 2048
  float* keyb  = ce + 2048;               // 12*1680*128 = 2,580,480
  float* valb  = keyb + 2580480;
  float* query = valb + 2580480;          // 12*2500*128 = 3,840,000
  float* qh    = query + 3840000;
  float* kh    = qh + 3840000;
  float* vh    = kh + 2580480;
  float* aout  = vh + 2580480;            // 2*2500*128 = 640,000

  k_cembed<<<12, 128, 0, stream>>>(W_cam, E_inv, ce);
  k_img<<<dim3(KK, 12), 128, 0, stream>>>(I_inv, E_inv, plane, W_img, ce, keyb);
  k_query<<<dim3(QQ, 12), 128, 0, stream>>>(bev_grid, W_bev, b_bev, ce, x, query);
  k_featconv<<<dim3(KK / TP, 12), 256, 0, stream>>>(feature,
      fp_g, fp_b, fp_m, fp_v, fl_g, fl_b, fl_m, fl_v, W_fproj, W_flin, keyb, valb);
  k_lnproj<<<(12 * QQ) / ROWS, 128, 0, stream>>>(query, q_ln_g, q_ln_b, Wq, bq, qh);
  k_lnproj<<<(12 * KK) / ROWS, 128, 0, stream>>>(keyb, k_ln_g, k_ln_b, Wk, bk, kh);
  k_lnproj<<<(12 * KK) / ROWS, 128, 0, stream>>>(valb, v_ln_g, v_ln_b, Wv, bv, vh);
  k_attn<<<dim3((QQ + QT - 1) / QT, NHEAD, NB), 256, 0, stream>>>(qh, kh, vh, aout);
  k_epi<<<NB * QQ, 128, 0, stream>>>(aout, x, Wproj, bproj, pre_g, pre_b,
                                     W1, b1, W2, b2, post_g, post_b, (float*)d_out);
}

// Round 3
// 1067.269 us; speedup vs baseline: 1.5607x; 1.5607x over previous
//
#include <hip/hip_runtime.h>

#define NB    2
#define NCAM  6
#define FD    256
#define KK    1680
#define DIMN  128
#define NHEAD 4
#define DHD   32
#define QQ    2500
#define SCALE 0.17677669529663687f

typedef short bf8 __attribute__((ext_vector_type(8)));
typedef float f4  __attribute__((ext_vector_type(4)));

__device__ __forceinline__ unsigned short f2bf(float f) {
  unsigned int u = __float_as_uint(f);
  unsigned int r = (u + 0x7fffu + ((u >> 16) & 1u)) >> 16;
  return (unsigned short)r;
}

// ---------- helpers ----------
__device__ __forceinline__ float blk_sum128(float v, float* red) {
  #pragma unroll
  for (int o = 32; o > 0; o >>= 1) v += __shfl_down(v, o);
  int t = threadIdx.x;
  if ((t & 63) == 0) red[t >> 6] = v;
  __syncthreads();
  float r = red[0] + red[1];
  __syncthreads();
  return r;
}

// ---------- K1: camera-center embedding ----------
__global__ void k_cembed(const float* __restrict__ W_cam, const float* __restrict__ E_inv,
                         float* __restrict__ ce) {
  int bn = blockIdx.x;
  int d  = threadIdx.x;
  const float* e = E_inv + bn * 16;
  float s = 0.f;
  #pragma unroll
  for (int c = 0; c < 4; ++c) s += W_cam[d * 4 + c] * e[c * 4 + 3];
  ce[bn * 128 + d] = s;
}

// ---------- K2: per-pixel ray embedding (normalized) -> key buffer ----------
__global__ void k_img(const float* __restrict__ I_inv, const float* __restrict__ E_inv,
                      const float* __restrict__ plane, const float* __restrict__ W_img,
                      const float* __restrict__ ce, float* __restrict__ key) {
  __shared__ float red[2];
  int p  = blockIdx.x;
  int bn = blockIdx.y;
  int d  = threadIdx.x;
  const float* Ii = I_inv + bn * 9;
  const float* Ei = E_inv + bn * 16;
  float pl0 = plane[p], pl1 = plane[KK + p], pl2 = plane[2 * KK + p];
  float c0 = Ii[0]*pl0 + Ii[1]*pl1 + Ii[2]*pl2;
  float c1 = Ii[3]*pl0 + Ii[4]*pl1 + Ii[5]*pl2;
  float c2 = Ii[6]*pl0 + Ii[7]*pl1 + Ii[8]*pl2;
  float d0 = Ei[0]*c0 + Ei[1]*c1 + Ei[2]*c2  + Ei[3];
  float d1 = Ei[4]*c0 + Ei[5]*c1 + Ei[6]*c2  + Ei[7];
  float d2 = Ei[8]*c0 + Ei[9]*c1 + Ei[10]*c2 + Ei[11];
  float d3 = Ei[12]*c0 + Ei[13]*c1 + Ei[14]*c2 + Ei[15];
  float v = W_img[d*4]*d0 + W_img[d*4+1]*d1 + W_img[d*4+2]*d2 + W_img[d*4+3]*d3
            - ce[bn * 128 + d];
  float ss = blk_sum128(v * v, red);
  float inv = 1.f / (sqrtf(ss) + 1e-7f);
  key[((size_t)bn * KK + p) * DIMN + d] = v * inv;
}

// ---------- K3: BEV positional embedding + x -> query buffer ----------
__global__ void k_query(const float* __restrict__ bev_grid, const float* __restrict__ W_bev,
                        const float* __restrict__ b_bev, const float* __restrict__ ce,
                        const float* __restrict__ x, float* __restrict__ query) {
  __shared__ float red[2];
  int q  = blockIdx.x;
  int bn = blockIdx.y;
  int b  = bn / NCAM;
  int d  = threadIdx.x;
  float g0 = bev_grid[q], g1 = bev_grid[QQ + q];
  float v = W_bev[d * 2] * g0 + W_bev[d * 2 + 1] * g1 + b_bev[d] - ce[bn * 128 + d];
  float ss = blk_sum128(v * v, red);
  float inv = 1.f / (sqrtf(ss) + 1e-7f);
  query[((size_t)bn * QQ + q) * DIMN + d] = v * inv + x[(size_t)(b * DIMN + d) * QQ + q];
}

// ---------- K4: BN+ReLU + dual 1x1 conv on feature; key += fproj, val = flin ----------
#define TP 16
__global__ void k_featconv(const float* __restrict__ feat,
                           const float* __restrict__ g1c, const float* __restrict__ b1c,
                           const float* __restrict__ m1c, const float* __restrict__ v1c,
                           const float* __restrict__ g2c, const float* __restrict__ b2c,
                           const float* __restrict__ m2c, const float* __restrict__ v2c,
                           const float* __restrict__ Wfp, const float* __restrict__ Wfl,
                           float* __restrict__ key, float* __restrict__ val) {
  __shared__ float sc1[FD], sh1[FD], sc2[FD], sh2[FD];
  __shared__ float t1[FD * (TP + 1)];
  __shared__ float t2[FD * (TP + 1)];
  int tile = blockIdx.x;
  int bn   = blockIdx.y;
  int t    = threadIdx.x;
  int p0   = tile * TP;
  {
    int c = t;
    float s1 = g1c[c] * rsqrtf(v1c[c] + 1e-5f);
    sc1[c] = s1; sh1[c] = b1c[c] - m1c[c] * s1;
    float s2 = g2c[c] * rsqrtf(v2c[c] + 1e-5f);
    sc2[c] = s2; sh2[c] = b2c[c] - m2c[c] * s2;
  }
  __syncthreads();
  const float* fb = feat + (size_t)bn * FD * KK + p0;
  int pp = t & 15, crow = t >> 4;
  #pragma unroll
  for (int i = 0; i < 16; ++i) {
    int c = i * 16 + crow;
    float raw = fb[(size_t)c * KK + pp];
    t1[c * (TP + 1) + pp] = fmaxf(raw * sc1[c] + sh1[c], 0.f);
    t2[c * (TP + 1) + pp] = fmaxf(raw * sc2[c] + sh2[c], 0.f);
  }
  __syncthreads();
  int dd = t & 127;
  const float4* W4 = (const float4*)((t < 128) ? Wfp : Wfl) + dd * 64;
  const float* tl = (t < 128) ? t1 : t2;
  float acc[TP];
  #pragma unroll
  for (int p = 0; p < TP; ++p) acc[p] = 0.f;
  for (int c4 = 0; c4 < 64; ++c4) {
    float4 w = W4[c4];
    const float* r0 = &tl[(c4 * 4 + 0) * (TP + 1)];
    const float* r1 = &tl[(c4 * 4 + 1) * (TP + 1)];
    const float* r2 = &tl[(c4 * 4 + 2) * (TP + 1)];
    const float* r3 = &tl[(c4 * 4 + 3) * (TP + 1)];
    #pragma unroll
    for (int p = 0; p < TP; ++p)
      acc[p] += w.x * r0[p] + w.y * r1[p] + w.z * r2[p] + w.w * r3[p];
  }
  __syncthreads();
  {
    float* dst = (t < 128) ? t1 : t2;
    #pragma unroll
    for (int p = 0; p < TP; ++p) dst[dd * (TP + 1) + p] = acc[p];
  }
  __syncthreads();
  #pragma unroll
  for (int i = 0; i < 16; ++i) {
    int e   = i * 256 + t;
    int ddo = e & 127, po = (e >> 7) & 15, wh = e >> 11;
    size_t addr = ((size_t)bn * KK + p0 + po) * DIMN + ddo;
    float vv = (wh ? t2 : t1)[ddo * (TP + 1) + po];
    if (wh) val[addr] = vv;
    else    key[addr] += vv;
  }
}

// ---------- K5: LayerNorm + 128x128 projection -> bf16 (MODE 0 row-major, MODE 1 V-transposed) ----------
#define ROWS 8
template<int MODE>
__global__ void k_lnproj_bf(const float* __restrict__ in, const float* __restrict__ lng,
                            const float* __restrict__ lnb, const float* __restrict__ W,
                            const float* __restrict__ bias, unsigned short* __restrict__ out,
                            float scale) {
  __shared__ float red[2];
  __shared__ float ln[ROWS][DIMN];
  __shared__ float stats[ROWS][2];
  size_t r0 = (size_t)blockIdx.x * ROWS;
  int t = threadIdx.x;
  float g = lng[t], bb = lnb[t];
  float xv[ROWS];
  #pragma unroll
  for (int r = 0; r < ROWS; ++r) xv[r] = in[(r0 + r) * DIMN + t];
  #pragma unroll
  for (int r = 0; r < ROWS; ++r) {
    float s  = blk_sum128(xv[r], red);
    float s2 = blk_sum128(xv[r] * xv[r], red);
    if (t == 0) { stats[r][0] = s * (1.f / 128.f); stats[r][1] = s2 * (1.f / 128.f); }
  }
  __syncthreads();
  #pragma unroll
  for (int r = 0; r < ROWS; ++r) {
    float mu  = stats[r][0];
    float var = fmaxf(stats[r][1] - mu * mu, 0.f);
    float rin = rsqrtf(var + 1e-5f);
    ln[r][t] = (xv[r] - mu) * rin * g + bb;
  }
  __syncthreads();
  float acc[ROWS];
  float bv = bias[t];
  #pragma unroll
  for (int r = 0; r < ROWS; ++r) acc[r] = bv;
  const float4* W4 = (const float4*)W + t * 32;
  for (int j4 = 0; j4 < 32; ++j4) {
    float4 w = W4[j4];
    #pragma unroll
    for (int r = 0; r < ROWS; ++r)
      acc[r] += w.x * ln[r][j4*4] + w.y * ln[r][j4*4+1] + w.z * ln[r][j4*4+2] + w.w * ln[r][j4*4+3];
  }
  if (MODE == 0) {
    #pragma unroll
    for (int r = 0; r < ROWS; ++r) out[(r0 + r) * DIMN + t] = f2bf(acc[r] * scale);
  } else {
    // V transposed: out[((bn*4+m)*32+d)*1680 + k], 8 consecutive k -> one 16B store
    int bn = (int)(r0 / KK), k0 = (int)(r0 % KK);
    int m = t >> 5, d = t & 31;
    unsigned int u0 = (unsigned int)f2bf(acc[0]) | ((unsigned int)f2bf(acc[1]) << 16);
    unsigned int u1 = (unsigned int)f2bf(acc[2]) | ((unsigned int)f2bf(acc[3]) << 16);
    unsigned int u2 = (unsigned int)f2bf(acc[4]) | ((unsigned int)f2bf(acc[5]) << 16);
    unsigned int u3 = (unsigned int)f2bf(acc[6]) | ((unsigned int)f2bf(acc[7]) << 16);
    uint4 pk = make_uint4(u0, u1, u2, u3);
    *(uint4*)&out[((size_t)((bn * 4 + m) * 32 + d)) * KK + k0] = pk;
  }
}

// ---------- K6: MFMA flash attention ----------
// 1 wave/block, 16 queries/wave. grid (157, 4, 2).
__global__ __launch_bounds__(64)
void k_attn_mfma(const unsigned short* __restrict__ qhB, const unsigned short* __restrict__ khB,
                 const unsigned short* __restrict__ vhB, float* __restrict__ aout) {
  __shared__ unsigned short pls[16 * 40];   // P transpose buffer, rows 80B (16B aligned)
  int qt = blockIdx.x, m = blockIdx.y, b = blockIdx.z;
  int l = threadIdx.x;
  int c = l & 15, g = l >> 4;
  int q0 = qt * 16;

  // Q frags (SCALE pre-folded), per camera
  bf8 qf[NCAM];
  #pragma unroll
  for (int n = 0; n < NCAM; ++n) {
    int q = q0 + c;
    if (q < QQ)
      qf[n] = *(const bf8*)&qhB[((size_t)(b * NCAM + n) * QQ + q) * DIMN + m * DHD + g * 8];
    else
      qf[n] = (bf8)0;
  }
  f4 o0 = {0.f, 0.f, 0.f, 0.f}, o1 = {0.f, 0.f, 0.f, 0.f};
  float mrun[4], lrun[4];
  #pragma unroll
  for (int i = 0; i < 4; ++i) { mrun[i] = -1e30f; lrun[i] = 0.f; }
  const f4 z4 = {0.f, 0.f, 0.f, 0.f};

  for (int n = 0; n < NCAM; ++n) {
    const unsigned short* kb = khB + (size_t)(b * NCAM + n) * KK * DIMN + m * DHD;
    const unsigned short* vb = vhB + (size_t)((b * NCAM + n) * NHEAD + m) * DHD * KK;
    bf8 qa = qf[n];
    for (int k0 = 0; k0 < KK; k0 += 32) {
      bool tail = (k0 + 32 > KK);   // last 16 keys only
      bf8 kf0 = *(const bf8*)&kb[(size_t)(k0 + c) * DIMN + g * 8];
      bf8 vf0 = *(const bf8*)&vb[(size_t)c * KK + k0 + g * 8];
      bf8 vf1 = *(const bf8*)&vb[(size_t)(16 + c) * KK + k0 + g * 8];
      f4 s0 = __builtin_amdgcn_mfma_f32_16x16x32_bf16(qa, kf0, z4, 0, 0, 0);
      f4 s1;
      if (!tail) {
        bf8 kf1 = *(const bf8*)&kb[(size_t)(k0 + 16 + c) * DIMN + g * 8];
        s1 = __builtin_amdgcn_mfma_f32_16x16x32_bf16(qa, kf1, z4, 0, 0, 0);
      } else {
        s1 = (f4){-1e30f, -1e30f, -1e30f, -1e30f};
      }
      #pragma unroll
      for (int i = 0; i < 4; ++i) {
        float a0 = s0[i], a1 = s1[i];
        float tm = fmaxf(a0, a1);
        #pragma unroll
        for (int msk = 1; msk < 16; msk <<= 1) tm = fmaxf(tm, __shfl_xor(tm, msk, 16));
        float mn = fmaxf(mrun[i], tm);
        float al = __expf(mrun[i] - mn);
        mrun[i] = mn;
        float p0 = __expf(a0 - mn);
        float p1 = __expf(a1 - mn);   // tail: exp(-1e30) = 0
        float ps = p0 + p1;
        #pragma unroll
        for (int msk = 1; msk < 16; msk <<= 1) ps += __shfl_xor(ps, msk, 16);
        lrun[i] = lrun[i] * al + ps;
        o0[i] *= al; o1[i] *= al;
        pls[(4 * g + i) * 40 + c]      = f2bf(p0);
        pls[(4 * g + i) * 40 + 16 + c] = f2bf(p1);
      }
      bf8 pa = *(const bf8*)&pls[c * 40 + g * 8];
      o0 = __builtin_amdgcn_mfma_f32_16x16x32_bf16(pa, vf0, o0, 0, 0, 0);
      o1 = __builtin_amdgcn_mfma_f32_16x16x32_bf16(pa, vf1, o1, 0, 0, 0);
    }
  }
  #pragma unroll
  for (int i = 0; i < 4; ++i) {
    int q = q0 + 4 * g + i;
    if (q < QQ) {
      float inv = 1.f / lrun[i];
      size_t o = ((size_t)b * QQ + q) * DIMN + m * DHD;
      aout[o + c]      = o0[i] * inv;
      aout[o + 16 + c] = o1[i] * inv;
    }
  }
}

// ---------- K7: epilogue ----------
__global__ void k_epi(const float* __restrict__ a, const float* __restrict__ x,
                      const float* __restrict__ Wproj, const float* __restrict__ bproj,
                      const float* __restrict__ preg, const float* __restrict__ preb,
                      const float* __restrict__ W1, const float* __restrict__ b1,
                      const float* __restrict__ W2, const float* __restrict__ b2,
                      const float* __restrict__ postg, const float* __restrict__ postb,
                      float* __restrict__ out) {
  __shared__ float red[2];
  __shared__ float sa[DIMN];
  __shared__ float sln[DIMN];
  __shared__ float sh[2 * DIMN];
  int row = blockIdx.x;
  int b = row / QQ, q = row % QQ;
  int t = threadIdx.x;
  sa[t] = a[(size_t)row * DIMN + t];
  __syncthreads();
  float z = bproj[t] + x[(size_t)(b * DIMN + t) * QQ + q];
  const float4* Wp4 = (const float4*)Wproj + t * 32;
  for (int j4 = 0; j4 < 32; ++j4) {
    float4 w = Wp4[j4];
    z += w.x * sa[j4*4] + w.y * sa[j4*4+1] + w.z * sa[j4*4+2] + w.w * sa[j4*4+3];
  }
  float mu  = blk_sum128(z, red) * (1.f / 128.f);
  float s2  = blk_sum128(z * z, red) * (1.f / 128.f);
  float var = fmaxf(s2 - mu * mu, 0.f);
  float ln1 = (z - mu) * rsqrtf(var + 1e-5f) * preg[t] + preb[t];
  sln[t] = ln1;
  __syncthreads();
  float h0 = b1[t], h1 = b1[t + 128];
  const float4* W1a = (const float4*)W1 + t * 32;
  const float4* W1b = (const float4*)W1 + (t + 128) * 32;
  for (int j4 = 0; j4 < 32; ++j4) {
    float4 wa = W1a[j4], wb = W1b[j4];
    float l0 = sln[j4*4], l1 = sln[j4*4+1], l2 = sln[j4*4+2], l3 = sln[j4*4+3];
    h0 += wa.x*l0 + wa.y*l1 + wa.z*l2 + wa.w*l3;
    h1 += wb.x*l0 + wb.y*l1 + wb.z*l2 + wb.w*l3;
  }
  h0 = 0.5f * h0 * (1.f + erff(h0 * 0.70710678118f));
  h1 = 0.5f * h1 * (1.f + erff(h1 * 0.70710678118f));
  sh[t] = h0; sh[t + 128] = h1;
  __syncthreads();
  float z2 = ln1 + b2[t];
  const float4* W24 = (const float4*)W2 + t * 64;
  for (int j4 = 0; j4 < 64; ++j4) {
    float4 w = W24[j4];
    z2 += w.x * sh[j4*4] + w.y * sh[j4*4+1] + w.z * sh[j4*4+2] + w.w * sh[j4*4+3];
  }
  mu  = blk_sum128(z2, red) * (1.f / 128.f);
  s2  = blk_sum128(z2 * z2, red) * (1.f / 128.f);
  var = fmaxf(s2 - mu * mu, 0.f);
  float o = (z2 - mu) * rsqrtf(var + 1e-5f) * postg[t] + postb[t];
  out[(size_t)(b * DIMN + t) * QQ + q] = o;
}

// ---------- launch ----------
extern "C" void kernel_launch(void* const* d_in, const int* in_sizes, int n_in,
                              void* d_out, int out_size, void* d_ws, size_t ws_size,
                              hipStream_t stream) {
  const float* x        = (const float*)d_in[0];
  const float* feature  = (const float*)d_in[1];
  const float* I_inv    = (const float*)d_in[2];
  const float* E_inv    = (const float*)d_in[3];
  const float* bev_grid = (const float*)d_in[4];
  const float* plane    = (const float*)d_in[5];
  const float* W_cam    = (const float*)d_in[6];
  const float* W_img    = (const float*)d_in[7];
  const float* W_bev    = (const float*)d_in[8];
  const float* b_bev    = (const float*)d_in[9];
  const float* fp_g = (const float*)d_in[10];
  const float* fp_b = (const float*)d_in[11];
  const float* fp_m = (const float*)d_in[12];
  const float* fp_v = (const float*)d_in[13];
  const float* fl_g = (const float*)d_in[14];
  const float* fl_b = (const float*)d_in[15];
  const float* fl_m = (const float*)d_in[16];
  const float* fl_v = (const float*)d_in[17];
  const float* W_fproj = (const float*)d_in[18];
  const float* W_flin  = (const float*)d_in[19];
  const float* q_ln_g = (const float*)d_in[20];
  const float* q_ln_b = (const float*)d_in[21];
  const float* Wq = (const float*)d_in[22];
  const float* bq = (const float*)d_in[23];
  const float* k_ln_g = (const float*)d_in[24];
  const float* k_ln_b = (const float*)d_in[25];
  const float* Wk = (const float*)d_in[26];
  const float* bk = (const float*)d_in[27];
  const float* v_ln_g = (const float*)d_in[28];
  const float* v_ln_b = (const float*)d_in[29];
  const float* Wv = (const float*)d_in[30];
  const float* bv = (const float*)d_in[31];
  const float* Wproj = (const float*)d_in[32];
  const float* bproj = (const float*)d_in[33];
  const float* pre_g = (const float*)d_in[34];
  const float* pre_b = (const float*)d_in[35];
  const float* W1 = (const float*)d_in[36];
  const float* b1 = (const float*)d_in[37];
  const float* W2 = (const float*)d_in[38];
  const float* b2 = (const float*)d_in[39];
  const float* post_g = (const float*)d_in[40];
  const float* post_b = (const float*)d_in[41];

  float* ws    = (float*)d_ws;
  float* ce    = ws;                       // 2048
  float* keyb  = ce + 2048;                // 2,580,480
  float* valb  = keyb + 2580480;           // 2,580,480
  float* query = valb + 2580480;           // 3,840,000
  float* aout  = query + 3840000;          // 640,000
  unsigned short* qhB = (unsigned short*)(aout + 640000);  // 3,840,000 u16
  unsigned short* khB = qhB + 3840000;                     // 2,580,480 u16
  unsigned short* vhB = khB + 2580480;                     // 2,580,480 u16 (+pad)

  k_cembed<<<12, 128, 0, stream>>>(W_cam, E_inv, ce);
  k_img<<<dim3(KK, 12), 128, 0, stream>>>(I_inv, E_inv, plane, W_img, ce, keyb);
  k_query<<<dim3(QQ, 12), 128, 0, stream>>>(bev_grid, W_bev, b_bev, ce, x, query);
  k_featconv<<<dim3(KK / TP, 12), 256, 0, stream>>>(feature,
      fp_g, fp_b, fp_m, fp_v, fl_g, fl_b, fl_m, fl_v, W_fproj, W_flin, keyb, valb);
  k_lnproj_bf<0><<<(12 * QQ) / ROWS, 128, 0, stream>>>(query, q_ln_g, q_ln_b, Wq, bq, qhB, SCALE);
  k_lnproj_bf<0><<<(12 * KK) / ROWS, 128, 0, stream>>>(keyb, k_ln_g, k_ln_b, Wk, bk, khB, 1.0f);
  k_lnproj_bf<1><<<(12 * KK) / ROWS, 128, 0, stream>>>(valb, v_ln_g, v_ln_b, Wv, bv, vhB, 1.0f);
  k_attn_mfma<<<dim3((QQ + 15) / 16, NHEAD, NB), 64, 0, stream>>>(qhB, khB, vhB, aout);
  k_epi<<<NB * QQ, 128, 0, stream>>>(aout, x, Wproj, bproj, pre_g, pre_b,
                                     W1, b1, W2, b2, post_g, post_b, (float*)d_out);
}

// Round 5
// 889.356 us; speedup vs baseline: 1.8729x; 1.2000x over previous
//
#include <hip/hip_runtime.h>

#define NB    2
#define NCAM  6
#define FD    256
#define KK    1680
#define DIMN  128
#define NHEAD 4
#define DHD   32
#define QQ    2500
#define SCALE 0.17677669529663687f

typedef short bf8 __attribute__((ext_vector_type(8)));
typedef float f4  __attribute__((ext_vector_type(4)));

__device__ __forceinline__ unsigned short f2bf(float f) {
  unsigned int u = __float_as_uint(f);
  unsigned int r = (u + 0x7fffu + ((u >> 16) & 1u)) >> 16;
  return (unsigned short)r;
}

// ---------- helpers ----------
__device__ __forceinline__ float blk_sum128(float v, float* red) {
  #pragma unroll
  for (int o = 32; o > 0; o >>= 1) v += __shfl_down(v, o);
  int t = threadIdx.x;
  if ((t & 63) == 0) red[t >> 6] = v;
  __syncthreads();
  float r = red[0] + red[1];
  __syncthreads();
  return r;
}

// ---------- K1: camera-center embedding ----------
__global__ void k_cembed(const float* __restrict__ W_cam, const float* __restrict__ E_inv,
                         float* __restrict__ ce) {
  int bn = blockIdx.x;
  int d  = threadIdx.x;
  const float* e = E_inv + bn * 16;
  float s = 0.f;
  #pragma unroll
  for (int c = 0; c < 4; ++c) s += W_cam[d * 4 + c] * e[c * 4 + 3];
  ce[bn * 128 + d] = s;
}

// ---------- K2: per-pixel ray embedding (normalized) -> key buffer ----------
__global__ void k_img(const float* __restrict__ I_inv, const float* __restrict__ E_inv,
                      const float* __restrict__ plane, const float* __restrict__ W_img,
                      const float* __restrict__ ce, float* __restrict__ key) {
  __shared__ float red[2];
  int p  = blockIdx.x;
  int bn = blockIdx.y;
  int d  = threadIdx.x;
  const float* Ii = I_inv + bn * 9;
  const float* Ei = E_inv + bn * 16;
  float pl0 = plane[p], pl1 = plane[KK + p], pl2 = plane[2 * KK + p];
  float c0 = Ii[0]*pl0 + Ii[1]*pl1 + Ii[2]*pl2;
  float c1 = Ii[3]*pl0 + Ii[4]*pl1 + Ii[5]*pl2;
  float c2 = Ii[6]*pl0 + Ii[7]*pl1 + Ii[8]*pl2;
  float d0 = Ei[0]*c0 + Ei[1]*c1 + Ei[2]*c2  + Ei[3];
  float d1 = Ei[4]*c0 + Ei[5]*c1 + Ei[6]*c2  + Ei[7];
  float d2 = Ei[8]*c0 + Ei[9]*c1 + Ei[10]*c2 + Ei[11];
  float d3 = Ei[12]*c0 + Ei[13]*c1 + Ei[14]*c2 + Ei[15];
  float v = W_img[d*4]*d0 + W_img[d*4+1]*d1 + W_img[d*4+2]*d2 + W_img[d*4+3]*d3
            - ce[bn * 128 + d];
  float ss = blk_sum128(v * v, red);
  float inv = 1.f / (sqrtf(ss) + 1e-7f);
  key[((size_t)bn * KK + p) * DIMN + d] = v * inv;
}

// ---------- K3: BEV positional embedding + x -> query buffer ----------
__global__ void k_query(const float* __restrict__ bev_grid, const float* __restrict__ W_bev,
                        const float* __restrict__ b_bev, const float* __restrict__ ce,
                        const float* __restrict__ x, float* __restrict__ query) {
  __shared__ float red[2];
  int q  = blockIdx.x;
  int bn = blockIdx.y;
  int b  = bn / NCAM;
  int d  = threadIdx.x;
  float g0 = bev_grid[q], g1 = bev_grid[QQ + q];
  float v = W_bev[d * 2] * g0 + W_bev[d * 2 + 1] * g1 + b_bev[d] - ce[bn * 128 + d];
  float ss = blk_sum128(v * v, red);
  float inv = 1.f / (sqrtf(ss) + 1e-7f);
  query[((size_t)bn * QQ + q) * DIMN + d] = v * inv + x[(size_t)(b * DIMN + d) * QQ + q];
}

// ---------- K4: BN+ReLU + dual 1x1 conv on feature; key += fproj, val = flin ----------
#define TP 16
__global__ void k_featconv(const float* __restrict__ feat,
                           const float* __restrict__ g1c, const float* __restrict__ b1c,
                           const float* __restrict__ m1c, const float* __restrict__ v1c,
                           const float* __restrict__ g2c, const float* __restrict__ b2c,
                           const float* __restrict__ m2c, const float* __restrict__ v2c,
                           const float* __restrict__ Wfp, const float* __restrict__ Wfl,
                           float* __restrict__ key, float* __restrict__ val) {
  __shared__ float sc1[FD], sh1[FD], sc2[FD], sh2[FD];
  __shared__ float t1[FD * (TP + 1)];
  __shared__ float t2[FD * (TP + 1)];
  int tile = blockIdx.x;
  int bn   = blockIdx.y;
  int t    = threadIdx.x;
  int p0   = tile * TP;
  {
    int c = t;
    float s1 = g1c[c] * rsqrtf(v1c[c] + 1e-5f);
    sc1[c] = s1; sh1[c] = b1c[c] - m1c[c] * s1;
    float s2 = g2c[c] * rsqrtf(v2c[c] + 1e-5f);
    sc2[c] = s2; sh2[c] = b2c[c] - m2c[c] * s2;
  }
  __syncthreads();
  const float* fb = feat + (size_t)bn * FD * KK + p0;
  int pp = t & 15, crow = t >> 4;
  #pragma unroll
  for (int i = 0; i < 16; ++i) {
    int c = i * 16 + crow;
    float raw = fb[(size_t)c * KK + pp];
    t1[c * (TP + 1) + pp] = fmaxf(raw * sc1[c] + sh1[c], 0.f);
    t2[c * (TP + 1) + pp] = fmaxf(raw * sc2[c] + sh2[c], 0.f);
  }
  __syncthreads();
  int dd = t & 127;
  const float4* W4 = (const float4*)((t < 128) ? Wfp : Wfl) + dd * 64;
  const float* tl = (t < 128) ? t1 : t2;
  float acc[TP];
  #pragma unroll
  for (int p = 0; p < TP; ++p) acc[p] = 0.f;
  for (int c4 = 0; c4 < 64; ++c4) {
    float4 w = W4[c4];
    const float* r0 = &tl[(c4 * 4 + 0) * (TP + 1)];
    const float* r1 = &tl[(c4 * 4 + 1) * (TP + 1)];
    const float* r2 = &tl[(c4 * 4 + 2) * (TP + 1)];
    const float* r3 = &tl[(c4 * 4 + 3) * (TP + 1)];
    #pragma unroll
    for (int p = 0; p < TP; ++p)
      acc[p] += w.x * r0[p] + w.y * r1[p] + w.z * r2[p] + w.w * r3[p];
  }
  __syncthreads();
  {
    float* dst = (t < 128) ? t1 : t2;
    #pragma unroll
    for (int p = 0; p < TP; ++p) dst[dd * (TP + 1) + p] = acc[p];
  }
  __syncthreads();
  #pragma unroll
  for (int i = 0; i < 16; ++i) {
    int e   = i * 256 + t;
    int ddo = e & 127, po = (e >> 7) & 15, wh = e >> 11;
    size_t addr = ((size_t)bn * KK + p0 + po) * DIMN + ddo;
    float vv = (wh ? t2 : t1)[ddo * (TP + 1) + po];
    if (wh) val[addr] = vv;
    else    key[addr] += vv;
  }
}

// ---------- K5: LayerNorm + 128x128 projection -> bf16 (MODE 0 row-major, MODE 1 V-transposed) ----------
#define ROWS 8
template<int MODE>
__global__ void k_lnproj_bf(const float* __restrict__ in, const float* __restrict__ lng,
                            const float* __restrict__ lnb, const float* __restrict__ W,
                            const float* __restrict__ bias, unsigned short* __restrict__ out,
                            float scale) {
  __shared__ float red[2];
  __shared__ float ln[ROWS][DIMN];
  __shared__ float stats[ROWS][2];
  size_t r0 = (size_t)blockIdx.x * ROWS;
  int t = threadIdx.x;
  float g = lng[t], bb = lnb[t];
  float xv[ROWS];
  #pragma unroll
  for (int r = 0; r < ROWS; ++r) xv[r] = in[(r0 + r) * DIMN + t];
  #pragma unroll
  for (int r = 0; r < ROWS; ++r) {
    float s  = blk_sum128(xv[r], red);
    float s2 = blk_sum128(xv[r] * xv[r], red);
    if (t == 0) { stats[r][0] = s * (1.f / 128.f); stats[r][1] = s2 * (1.f / 128.f); }
  }
  __syncthreads();
  #pragma unroll
  for (int r = 0; r < ROWS; ++r) {
    float mu  = stats[r][0];
    float var = fmaxf(stats[r][1] - mu * mu, 0.f);
    float rin = rsqrtf(var + 1e-5f);
    ln[r][t] = (xv[r] - mu) * rin * g + bb;
  }
  __syncthreads();
  float acc[ROWS];
  float bv = bias[t];
  #pragma unroll
  for (int r = 0; r < ROWS; ++r) acc[r] = bv;
  const float4* W4 = (const float4*)W + t * 32;
  for (int j4 = 0; j4 < 32; ++j4) {
    float4 w = W4[j4];
    #pragma unroll
    for (int r = 0; r < ROWS; ++r)
      acc[r] += w.x * ln[r][j4*4] + w.y * ln[r][j4*4+1] + w.z * ln[r][j4*4+2] + w.w * ln[r][j4*4+3];
  }
  if (MODE == 0) {
    #pragma unroll
    for (int r = 0; r < ROWS; ++r) out[(r0 + r) * DIMN + t] = f2bf(acc[r] * scale);
  } else {
    // V transposed: out[((bn*4+m)*32+d)*1680 + k], 8 consecutive k -> one 16B store
    int bn = (int)(r0 / KK), k0 = (int)(r0 % KK);
    int m = t >> 5, d = t & 31;
    unsigned int u0 = (unsigned int)f2bf(acc[0]) | ((unsigned int)f2bf(acc[1]) << 16);
    unsigned int u1 = (unsigned int)f2bf(acc[2]) | ((unsigned int)f2bf(acc[3]) << 16);
    unsigned int u2 = (unsigned int)f2bf(acc[4]) | ((unsigned int)f2bf(acc[5]) << 16);
    unsigned int u3 = (unsigned int)f2bf(acc[6]) | ((unsigned int)f2bf(acc[7]) << 16);
    uint4 pk = make_uint4(u0, u1, u2, u3);
    *(uint4*)&out[((size_t)((bn * 4 + m) * 32 + d)) * KK + k0] = pk;
  }
}

// ---------- K6: MFMA flash attention, 8-way split-K within a block ----------
// block 512 thr = 8 waves; wave w handles 32-key chunks j%8==w; merge partials in LDS.
#define AW 8
#define NCHUNK 53   // ceil(1680/32); chunk 52 has 16 keys
__global__ __launch_bounds__(512)
void k_attn_mfma(const unsigned short* __restrict__ qhB, const unsigned short* __restrict__ khB,
                 const unsigned short* __restrict__ vhB, float* __restrict__ aout) {
  __shared__ unsigned short pls[AW][16 * 40];   // per-wave P transpose buffer
  __shared__ float lds_o[AW][16][32];           // unnormalized o partials
  __shared__ float lds_m[AW][16], lds_l[AW][16];
  int qt = blockIdx.x, m = blockIdx.y, b = blockIdx.z;
  int t = threadIdx.x;
  int w = t >> 6, l = t & 63;
  int c = l & 15, g = l >> 4;
  int q0 = qt * 16;

  bf8 qf[NCAM];
  #pragma unroll
  for (int n = 0; n < NCAM; ++n) {
    int q = q0 + c;
    if (q < QQ)
      qf[n] = *(const bf8*)&qhB[((size_t)(b * NCAM + n) * QQ + q) * DIMN + m * DHD + g * 8];
    else
      qf[n] = (bf8)0;
  }
  f4 o0 = {0.f, 0.f, 0.f, 0.f}, o1 = {0.f, 0.f, 0.f, 0.f};
  float mrun[4], lrun[4];
  #pragma unroll
  for (int i = 0; i < 4; ++i) { mrun[i] = -1e30f; lrun[i] = 0.f; }
  const f4 z4 = {0.f, 0.f, 0.f, 0.f};

  for (int n = 0; n < NCAM; ++n) {
    const unsigned short* kb = khB + (size_t)(b * NCAM + n) * KK * DIMN + m * DHD;
    const unsigned short* vb = vhB + (size_t)((b * NCAM + n) * NHEAD + m) * DHD * KK;
    bf8 qa = qf[n];
    for (int j = w; j < NCHUNK; j += AW) {
      int k0 = j * 32;
      bool tail = (j == NCHUNK - 1);
      bf8 kf0 = *(const bf8*)&kb[(size_t)(k0 + c) * DIMN + g * 8];
      bf8 vf0 = *(const bf8*)&vb[(size_t)c * KK + k0 + g * 8];
      bf8 vf1 = *(const bf8*)&vb[(size_t)(16 + c) * KK + k0 + g * 8];
      f4 s0 = __builtin_amdgcn_mfma_f32_16x16x32_bf16(qa, kf0, z4, 0, 0, 0);
      f4 s1;
      if (!tail) {
        bf8 kf1 = *(const bf8*)&kb[(size_t)(k0 + 16 + c) * DIMN + g * 8];
        s1 = __builtin_amdgcn_mfma_f32_16x16x32_bf16(qa, kf1, z4, 0, 0, 0);
      } else {
        s1 = (f4){-1e30f, -1e30f, -1e30f, -1e30f};
      }
      #pragma unroll
      for (int i = 0; i < 4; ++i) {
        float a0 = s0[i], a1 = s1[i];
        float tm = fmaxf(a0, a1);
        #pragma unroll
        for (int msk = 1; msk < 16; msk <<= 1) tm = fmaxf(tm, __shfl_xor(tm, msk, 16));
        float mn = fmaxf(mrun[i], tm);
        float al = __expf(mrun[i] - mn);
        mrun[i] = mn;
        float p0 = __expf(a0 - mn);
        float p1 = __expf(a1 - mn);   // tail: exp(-1e30) = 0
        float ps = p0 + p1;
        #pragma unroll
        for (int msk = 1; msk < 16; msk <<= 1) ps += __shfl_xor(ps, msk, 16);
        lrun[i] = lrun[i] * al + ps;
        o0[i] *= al; o1[i] *= al;
        pls[w][(4 * g + i) * 40 + c]      = f2bf(p0);
        pls[w][(4 * g + i) * 40 + 16 + c] = f2bf(p1);
      }
      bf8 pa = *(const bf8*)&pls[w][c * 40 + g * 8];
      o0 = __builtin_amdgcn_mfma_f32_16x16x32_bf16(pa, vf0, o0, 0, 0, 0);
      o1 = __builtin_amdgcn_mfma_f32_16x16x32_bf16(pa, vf1, o1, 0, 0, 0);
    }
  }
  // dump per-wave partials (unnormalized)
  #pragma unroll
  for (int i = 0; i < 4; ++i) {
    int qr = 4 * g + i;
    if (c == 0) { lds_m[w][qr] = mrun[i]; lds_l[w][qr] = lrun[i]; }
    lds_o[w][qr][c]      = o0[i];
    lds_o[w][qr][16 + c] = o1[i];
  }
  __syncthreads();
  // merge: 512 threads = 16 q x 32 d
  {
    int q = t >> 5, d = t & 31;
    float mg = -1e30f;
    #pragma unroll
    for (int ww = 0; ww < AW; ++ww) mg = fmaxf(mg, lds_m[ww][q]);
    float lg = 0.f, og = 0.f;
    #pragma unroll
    for (int ww = 0; ww < AW; ++ww) {
      float sc = __expf(lds_m[ww][q] - mg);
      lg += lds_l[ww][q] * sc;
      og += lds_o[ww][q][d] * sc;
    }
    int qq = q0 + q;
    if (qq < QQ)
      aout[((size_t)b * QQ + qq) * DIMN + m * DHD + d] = og / lg;
  }
}

// ---------- K7: epilogue ----------
__global__ void k_epi(const float* __restrict__ a, const float* __restrict__ x,
                      const float* __restrict__ Wproj, const float* __restrict__ bproj,
                      const float* __restrict__ preg, const float* __restrict__ preb,
                      const float* __restrict__ W1, const float* __restrict__ b1,
                      const float* __restrict__ W2, const float* __restrict__ b2,
                      const float* __restrict__ postg, const float* __restrict__ postb,
                      float* __restrict__ out) {
  __shared__ float red[2];
  __shared__ float sa[DIMN];
  __shared__ float sln[DIMN];
  __shared__ float sh[2 * DIMN];
  int row = blockIdx.x;
  int b = row / QQ, q = row % QQ;
  int t = threadIdx.x;
  sa[t] = a[(size_t)row * DIMN + t];
  __syncthreads();
  float z = bproj[t] + x[(size_t)(b * DIMN + t) * QQ + q];
  const float4* Wp4 = (const float4*)Wproj + t * 32;
  for (int j4 = 0; j4 < 32; ++j4) {
    float4 w = Wp4[j4];
    z += w.x * sa[j4*4] + w.y * sa[j4*4+1] + w.z * sa[j4*4+2] + w.w * sa[j4*4+3];
  }
  float mu  = blk_sum128(z, red) * (1.f / 128.f);
  float s2  = blk_sum128(z * z, red) * (1.f / 128.f);
  float var = fmaxf(s2 - mu * mu, 0.f);
  float ln1 = (z - mu) * rsqrtf(var + 1e-5f) * preg[t] + preb[t];
  sln[t] = ln1;
  __syncthreads();
  float h0 = b1[t], h1 = b1[t + 128];
  const float4* W1a = (const float4*)W1 + t * 32;
  const float4* W1b = (const float4*)W1 + (t + 128) * 32;
  for (int j4 = 0; j4 < 32; ++j4) {
    float4 wa = W1a[j4], wb = W1b[j4];
    float l0 = sln[j4*4], l1 = sln[j4*4+1], l2 = sln[j4*4+2], l3 = sln[j4*4+3];
    h0 += wa.x*l0 + wa.y*l1 + wa.z*l2 + wa.w*l3;
    h1 += wb.x*l0 + wb.y*l1 + wb.z*l2 + wb.w*l3;
  }
  h0 = 0.5f * h0 * (1.f + erff(h0 * 0.70710678118f));
  h1 = 0.5f * h1 * (1.f + erff(h1 * 0.70710678118f));
  sh[t] = h0; sh[t + 128] = h1;
  __syncthreads();
  float z2 = ln1 + b2[t];
  const float4* W24 = (const float4*)W2 + t * 64;
  for (int j4 = 0; j4 < 64; ++j4) {
    float4 w = W24[j4];
    z2 += w.x * sh[j4*4] + w.y * sh[j4*4+1] + w.z * sh[j4*4+2] + w.w * sh[j4*4+3];
  }
  mu  = blk_sum128(z2, red) * (1.f / 128.f);
  s2  = blk_sum128(z2 * z2, red) * (1.f / 128.f);
  var = fmaxf(s2 - mu * mu, 0.f);
  float o = (z2 - mu) * rsqrtf(var + 1e-5f) * postg[t] + postb[t];
  out[(size_t)(b * DIMN + t) * QQ + q] = o;
}

// ---------- launch ----------
extern "C" void kernel_launch(void* const* d_in, const int* in_sizes, int n_in,
                              void* d_out, int out_size, void* d_ws, size_t ws_size,
                              hipStream_t stream) {
  const float* x        = (const float*)d_in[0];
  const float* feature  = (const float*)d_in[1];
  const float* I_inv    = (const float*)d_in[2];
  const float* E_inv    = (const float*)d_in[3];
  const float* bev_grid = (const float*)d_in[4];
  const float* plane    = (const float*)d_in[5];
  const float* W_cam    = (const float*)d_in[6];
  const float* W_img    = (const float*)d_in[7];
  const float* W_bev    = (const float*)d_in[8];
  const float* b_bev    = (const float*)d_in[9];
  const float* fp_g = (const float*)d_in[10];
  const float* fp_b = (const float*)d_in[11];
  const float* fp_m = (const float*)d_in[12];
  const float* fp_v = (const float*)d_in[13];
  const float* fl_g = (const float*)d_in[14];
  const float* fl_b = (const float*)d_in[15];
  const float* fl_m = (const float*)d_in[16];
  const float* fl_v = (const float*)d_in[17];
  const float* W_fproj = (const float*)d_in[18];
  const float* W_flin  = (const float*)d_in[19];
  const float* q_ln_g = (const float*)d_in[20];
  const float* q_ln_b = (const float*)d_in[21];
  const float* Wq = (const float*)d_in[22];
  const float* bq = (const float*)d_in[23];
  const float* k_ln_g = (const float*)d_in[24];
  const float* k_ln_b = (const float*)d_in[25];
  const float* Wk = (const float*)d_in[26];
  const float* bk = (const float*)d_in[27];
  const float* v_ln_g = (const float*)d_in[28];
  const float* v_ln_b = (const float*)d_in[29];
  const float* Wv = (const float*)d_in[30];
  const float* bv = (const float*)d_in[31];
  const float* Wproj = (const float*)d_in[32];
  const float* bproj = (const float*)d_in[33];
  const float* pre_g = (const float*)d_in[34];
  const float* pre_b = (const float*)d_in[35];
  const float* W1 = (const float*)d_in[36];
  const float* b1 = (const float*)d_in[37];
  const float* W2 = (const float*)d_in[38];
  const float* b2 = (const float*)d_in[39];
  const float* post_g = (const float*)d_in[40];
  const float* post_b = (const float*)d_in[41];

  float* ws    = (float*)d_ws;
  float* ce    = ws;                       // 2048
  float* keyb  = ce + 2048;                // 2,580,480
  float* valb  = keyb + 2580480;           // 2,580,480
  float* query = valb + 2580480;           // 3,840,000
  float* aout  = query + 3840000;          // 640,000
  unsigned short* qhB = (unsigned short*)(aout + 640000);  // 3,840,000 u16
  unsigned short* vhB = qhB + 3840000;                     // 2,580,480 u16 (tail OOB spills into khB: safe)
  unsigned short* khB = vhB + 2580480;                     // 2,580,480 u16

  k_cembed<<<12, 128, 0, stream>>>(W_cam, E_inv, ce);
  k_img<<<dim3(KK, 12), 128, 0, stream>>>(I_inv, E_inv, plane, W_img, ce, keyb);
  k_query<<<dim3(QQ, 12), 128, 0, stream>>>(bev_grid, W_bev, b_bev, ce, x, query);
  k_featconv<<<dim3(KK / TP, 12), 256, 0, stream>>>(feature,
      fp_g, fp_b, fp_m, fp_v, fl_g, fl_b, fl_m, fl_v, W_fproj, W_flin, keyb, valb);
  k_lnproj_bf<0><<<(12 * QQ) / ROWS, 128, 0, stream>>>(query, q_ln_g, q_ln_b, Wq, bq, qhB, SCALE);
  k_lnproj_bf<0><<<(12 * KK) / ROWS, 128, 0, stream>>>(keyb, k_ln_g, k_ln_b, Wk, bk, khB, 1.0f);
  k_lnproj_bf<1><<<(12 * KK) / ROWS, 128, 0, stream>>>(valb, v_ln_g, v_ln_b, Wv, bv, vhB, 1.0f);
  k_attn_mfma<<<dim3((QQ + 15) / 16, NHEAD, NB), 512, 0, stream>>>(qhB, khB, vhB, aout);
  k_epi<<<NB * QQ, 128, 0, stream>>>(aout, x, Wproj, bproj, pre_g, pre_b,
                                     W1, b1, W2, b2, post_g, post_b, (float*)d_out);
}

// Round 6
// 622.155 us; speedup vs baseline: 2.6772x; 1.4295x over previous
//
#include <hip/hip_runtime.h>

#define NB    2
#define NCAM  6
#define FD    256
#define KK    1680
#define DIMN  128
#define NHEAD 4
#define DHD   32
#define QQ    2500
#define SCALE 0.17677669529663687f

typedef short bf8 __attribute__((ext_vector_type(8)));
typedef float f4  __attribute__((ext_vector_type(4)));

__device__ __forceinline__ unsigned short f2bf(float f) {
  unsigned int u = __float_as_uint(f);
  unsigned int r = (u + 0x7fffu + ((u >> 16) & 1u)) >> 16;
  return (unsigned short)r;
}

// ---------- helpers ----------
__device__ __forceinline__ float blk_sum128(float v, float* red) {
  #pragma unroll
  for (int o = 32; o > 0; o >>= 1) v += __shfl_down(v, o);
  int t = threadIdx.x;
  if ((t & 63) == 0) red[t >> 6] = v;
  __syncthreads();
  float r = red[0] + red[1];
  __syncthreads();
  return r;
}

// ---------- K1: camera-center embedding ----------
__global__ void k_cembed(const float* __restrict__ W_cam, const float* __restrict__ E_inv,
                         float* __restrict__ ce) {
  int bn = blockIdx.x;
  int d  = threadIdx.x;
  const float* e = E_inv + bn * 16;
  float s = 0.f;
  #pragma unroll
  for (int c = 0; c < 4; ++c) s += W_cam[d * 4 + c] * e[c * 4 + 3];
  ce[bn * 128 + d] = s;
}

// ---------- K2: per-pixel ray embedding (normalized) -> key buffer ----------
__global__ void k_img(const float* __restrict__ I_inv, const float* __restrict__ E_inv,
                      const float* __restrict__ plane, const float* __restrict__ W_img,
                      const float* __restrict__ ce, float* __restrict__ key) {
  __shared__ float red[2];
  int p  = blockIdx.x;
  int bn = blockIdx.y;
  int d  = threadIdx.x;
  const float* Ii = I_inv + bn * 9;
  const float* Ei = E_inv + bn * 16;
  float pl0 = plane[p], pl1 = plane[KK + p], pl2 = plane[2 * KK + p];
  float c0 = Ii[0]*pl0 + Ii[1]*pl1 + Ii[2]*pl2;
  float c1 = Ii[3]*pl0 + Ii[4]*pl1 + Ii[5]*pl2;
  float c2 = Ii[6]*pl0 + Ii[7]*pl1 + Ii[8]*pl2;
  float d0 = Ei[0]*c0 + Ei[1]*c1 + Ei[2]*c2  + Ei[3];
  float d1 = Ei[4]*c0 + Ei[5]*c1 + Ei[6]*c2  + Ei[7];
  float d2 = Ei[8]*c0 + Ei[9]*c1 + Ei[10]*c2 + Ei[11];
  float d3 = Ei[12]*c0 + Ei[13]*c1 + Ei[14]*c2 + Ei[15];
  float v = W_img[d*4]*d0 + W_img[d*4+1]*d1 + W_img[d*4+2]*d2 + W_img[d*4+3]*d3
            - ce[bn * 128 + d];
  float ss = blk_sum128(v * v, red);
  float inv = 1.f / (sqrtf(ss) + 1e-7f);
  key[((size_t)bn * KK + p) * DIMN + d] = v * inv;
}

// ---------- K3: BEV positional embedding + x -> query buffer ----------
__global__ void k_query(const float* __restrict__ bev_grid, const float* __restrict__ W_bev,
                        const float* __restrict__ b_bev, const float* __restrict__ ce,
                        const float* __restrict__ x, float* __restrict__ query) {
  __shared__ float red[2];
  int q  = blockIdx.x;
  int bn = blockIdx.y;
  int b  = bn / NCAM;
  int d  = threadIdx.x;
  float g0 = bev_grid[q], g1 = bev_grid[QQ + q];
  float v = W_bev[d * 2] * g0 + W_bev[d * 2 + 1] * g1 + b_bev[d] - ce[bn * 128 + d];
  float ss = blk_sum128(v * v, red);
  float inv = 1.f / (sqrtf(ss) + 1e-7f);
  query[((size_t)bn * QQ + q) * DIMN + d] = v * inv + x[(size_t)(b * DIMN + d) * QQ + q];
}

// ---------- K4: BN+ReLU + dual 1x1 conv on feature; key += fproj, val = flin ----------
#define TP 16
__global__ void k_featconv(const float* __restrict__ feat,
                           const float* __restrict__ g1c, const float* __restrict__ b1c,
                           const float* __restrict__ m1c, const float* __restrict__ v1c,
                           const float* __restrict__ g2c, const float* __restrict__ b2c,
                           const float* __restrict__ m2c, const float* __restrict__ v2c,
                           const float* __restrict__ Wfp, const float* __restrict__ Wfl,
                           float* __restrict__ key, float* __restrict__ val) {
  __shared__ float sc1[FD], sh1[FD], sc2[FD], sh2[FD];
  __shared__ float t1[FD * (TP + 1)];
  __shared__ float t2[FD * (TP + 1)];
  int tile = blockIdx.x;
  int bn   = blockIdx.y;
  int t    = threadIdx.x;
  int p0   = tile * TP;
  {
    int c = t;
    float s1 = g1c[c] * rsqrtf(v1c[c] + 1e-5f);
    sc1[c] = s1; sh1[c] = b1c[c] - m1c[c] * s1;
    float s2 = g2c[c] * rsqrtf(v2c[c] + 1e-5f);
    sc2[c] = s2; sh2[c] = b2c[c] - m2c[c] * s2;
  }
  __syncthreads();
  const float* fb = feat + (size_t)bn * FD * KK + p0;
  int pp = t & 15, crow = t >> 4;
  #pragma unroll
  for (int i = 0; i < 16; ++i) {
    int c = i * 16 + crow;
    float raw = fb[(size_t)c * KK + pp];
    t1[c * (TP + 1) + pp] = fmaxf(raw * sc1[c] + sh1[c], 0.f);
    t2[c * (TP + 1) + pp] = fmaxf(raw * sc2[c] + sh2[c], 0.f);
  }
  __syncthreads();
  int dd = t & 127;
  const float4* W4 = (const float4*)((t < 128) ? Wfp : Wfl) + dd * 64;
  const float* tl = (t < 128) ? t1 : t2;
  float acc[TP];
  #pragma unroll
  for (int p = 0; p < TP; ++p) acc[p] = 0.f;
  for (int c4 = 0; c4 < 64; ++c4) {
    float4 w = W4[c4];
    const float* r0 = &tl[(c4 * 4 + 0) * (TP + 1)];
    const float* r1 = &tl[(c4 * 4 + 1) * (TP + 1)];
    const float* r2 = &tl[(c4 * 4 + 2) * (TP + 1)];
    const float* r3 = &tl[(c4 * 4 + 3) * (TP + 1)];
    #pragma unroll
    for (int p = 0; p < TP; ++p)
      acc[p] += w.x * r0[p] + w.y * r1[p] + w.z * r2[p] + w.w * r3[p];
  }
  __syncthreads();
  {
    float* dst = (t < 128) ? t1 : t2;
    #pragma unroll
    for (int p = 0; p < TP; ++p) dst[dd * (TP + 1) + p] = acc[p];
  }
  __syncthreads();
  #pragma unroll
  for (int i = 0; i < 16; ++i) {
    int e   = i * 256 + t;
    int ddo = e & 127, po = (e >> 7) & 15, wh = e >> 11;
    size_t addr = ((size_t)bn * KK + p0 + po) * DIMN + ddo;
    float vv = (wh ? t2 : t1)[ddo * (TP + 1) + po];
    if (wh) val[addr] = vv;
    else    key[addr] += vv;
  }
}

// ---------- K5: LayerNorm + 128x128 projection -> bf16 (MODE 0 row-major, MODE 1 V-transposed) ----------
#define ROWS 8
template<int MODE>
__global__ void k_lnproj_bf(const float* __restrict__ in, const float* __restrict__ lng,
                            const float* __restrict__ lnb, const float* __restrict__ W,
                            const float* __restrict__ bias, unsigned short* __restrict__ out,
                            float scale) {
  __shared__ float red[2];
  __shared__ float ln[ROWS][DIMN];
  __shared__ float stats[ROWS][2];
  size_t r0 = (size_t)blockIdx.x * ROWS;
  int t = threadIdx.x;
  float g = lng[t], bb = lnb[t];
  float xv[ROWS];
  #pragma unroll
  for (int r = 0; r < ROWS; ++r) xv[r] = in[(r0 + r) * DIMN + t];
  #pragma unroll
  for (int r = 0; r < ROWS; ++r) {
    float s  = blk_sum128(xv[r], red);
    float s2 = blk_sum128(xv[r] * xv[r], red);
    if (t == 0) { stats[r][0] = s * (1.f / 128.f); stats[r][1] = s2 * (1.f / 128.f); }
  }
  __syncthreads();
  #pragma unroll
  for (int r = 0; r < ROWS; ++r) {
    float mu  = stats[r][0];
    float var = fmaxf(stats[r][1] - mu * mu, 0.f);
    float rin = rsqrtf(var + 1e-5f);
    ln[r][t] = (xv[r] - mu) * rin * g + bb;
  }
  __syncthreads();
  float acc[ROWS];
  float bv = bias[t];
  #pragma unroll
  for (int r = 0; r < ROWS; ++r) acc[r] = bv;
  const float4* W4 = (const float4*)W + t * 32;
  for (int j4 = 0; j4 < 32; ++j4) {
    float4 w = W4[j4];
    #pragma unroll
    for (int r = 0; r < ROWS; ++r)
      acc[r] += w.x * ln[r][j4*4] + w.y * ln[r][j4*4+1] + w.z * ln[r][j4*4+2] + w.w * ln[r][j4*4+3];
  }
  if (MODE == 0) {
    #pragma unroll
    for (int r = 0; r < ROWS; ++r) out[(r0 + r) * DIMN + t] = f2bf(acc[r] * scale);
  } else {
    // V transposed: out[((bn*4+m)*32+d)*1680 + k], 8 consecutive k -> one 16B store
    int bn = (int)(r0 / KK), k0 = (int)(r0 % KK);
    int m = t >> 5, d = t & 31;
    unsigned int u0 = (unsigned int)f2bf(acc[0]) | ((unsigned int)f2bf(acc[1]) << 16);
    unsigned int u1 = (unsigned int)f2bf(acc[2]) | ((unsigned int)f2bf(acc[3]) << 16);
    unsigned int u2 = (unsigned int)f2bf(acc[4]) | ((unsigned int)f2bf(acc[5]) << 16);
    unsigned int u3 = (unsigned int)f2bf(acc[6]) | ((unsigned int)f2bf(acc[7]) << 16);
    uint4 pk = make_uint4(u0, u1, u2, u3);
    *(uint4*)&out[((size_t)((bn * 4 + m) * 32 + d)) * KK + k0] = pk;
  }
}

// ---------- K6: MFMA flash attention, 8-way split-K within a block ----------
#define AW 8
#define NCHUNK 53   // ceil(1680/32); chunk 52 has 16 keys
__global__ __launch_bounds__(512)
void k_attn_mfma(const unsigned short* __restrict__ qhB, const unsigned short* __restrict__ khB,
                 const unsigned short* __restrict__ vhB, float* __restrict__ aout) {
  __shared__ unsigned short pls[AW][16 * 40];   // per-wave P transpose buffer
  __shared__ float lds_o[AW][16][32];           // unnormalized o partials
  __shared__ float lds_m[AW][16], lds_l[AW][16];
  int qt = blockIdx.x, m = blockIdx.y, b = blockIdx.z;
  int t = threadIdx.x;
  int w = t >> 6, l = t & 63;
  int c = l & 15, g = l >> 4;
  int q0 = qt * 16;

  bf8 qf[NCAM];
  #pragma unroll
  for (int n = 0; n < NCAM; ++n) {
    int q = q0 + c;
    if (q < QQ)
      qf[n] = *(const bf8*)&qhB[((size_t)(b * NCAM + n) * QQ + q) * DIMN + m * DHD + g * 8];
    else
      qf[n] = (bf8)0;
  }
  f4 o0 = {0.f, 0.f, 0.f, 0.f}, o1 = {0.f, 0.f, 0.f, 0.f};
  float mrun[4], lrun[4];
  #pragma unroll
  for (int i = 0; i < 4; ++i) { mrun[i] = -1e30f; lrun[i] = 0.f; }
  const f4 z4 = {0.f, 0.f, 0.f, 0.f};

  for (int n = 0; n < NCAM; ++n) {
    const unsigned short* kb = khB + (size_t)(b * NCAM + n) * KK * DIMN + m * DHD;
    const unsigned short* vb = vhB + (size_t)((b * NCAM + n) * NHEAD + m) * DHD * KK;
    bf8 qa = qf[n];
    for (int j = w; j < NCHUNK; j += AW) {
      int k0 = j * 32;
      bool tail = (j == NCHUNK - 1);
      bf8 kf0 = *(const bf8*)&kb[(size_t)(k0 + c) * DIMN + g * 8];
      bf8 vf0 = *(const bf8*)&vb[(size_t)c * KK + k0 + g * 8];
      bf8 vf1 = *(const bf8*)&vb[(size_t)(16 + c) * KK + k0 + g * 8];
      f4 s0 = __builtin_amdgcn_mfma_f32_16x16x32_bf16(qa, kf0, z4, 0, 0, 0);
      f4 s1;
      if (!tail) {
        bf8 kf1 = *(const bf8*)&kb[(size_t)(k0 + 16 + c) * DIMN + g * 8];
        s1 = __builtin_amdgcn_mfma_f32_16x16x32_bf16(qa, kf1, z4, 0, 0, 0);
      } else {
        s1 = (f4){-1e30f, -1e30f, -1e30f, -1e30f};
      }
      #pragma unroll
      for (int i = 0; i < 4; ++i) {
        float a0 = s0[i], a1 = s1[i];
        float tm = fmaxf(a0, a1);
        #pragma unroll
        for (int msk = 1; msk < 16; msk <<= 1) tm = fmaxf(tm, __shfl_xor(tm, msk, 16));
        float mn = fmaxf(mrun[i], tm);
        float al = __expf(mrun[i] - mn);
        mrun[i] = mn;
        float p0 = __expf(a0 - mn);
        float p1 = __expf(a1 - mn);   // tail: exp(-1e30) = 0
        float ps = p0 + p1;
        #pragma unroll
        for (int msk = 1; msk < 16; msk <<= 1) ps += __shfl_xor(ps, msk, 16);
        lrun[i] = lrun[i] * al + ps;
        o0[i] *= al; o1[i] *= al;
        pls[w][(4 * g + i) * 40 + c]      = f2bf(p0);
        pls[w][(4 * g + i) * 40 + 16 + c] = f2bf(p1);
      }
      bf8 pa = *(const bf8*)&pls[w][c * 40 + g * 8];
      o0 = __builtin_amdgcn_mfma_f32_16x16x32_bf16(pa, vf0, o0, 0, 0, 0);
      o1 = __builtin_amdgcn_mfma_f32_16x16x32_bf16(pa, vf1, o1, 0, 0, 0);
    }
  }
  #pragma unroll
  for (int i = 0; i < 4; ++i) {
    int qr = 4 * g + i;
    if (c == 0) { lds_m[w][qr] = mrun[i]; lds_l[w][qr] = lrun[i]; }
    lds_o[w][qr][c]      = o0[i];
    lds_o[w][qr][16 + c] = o1[i];
  }
  __syncthreads();
  {
    int q = t >> 5, d = t & 31;
    float mg = -1e30f;
    #pragma unroll
    for (int ww = 0; ww < AW; ++ww) mg = fmaxf(mg, lds_m[ww][q]);
    float lg = 0.f, og = 0.f;
    #pragma unroll
    for (int ww = 0; ww < AW; ++ww) {
      float sc = __expf(lds_m[ww][q] - mg);
      lg += lds_l[ww][q] * sc;
      og += lds_o[ww][q][d] * sc;
    }
    int qq = q0 + q;
    if (qq < QQ)
      aout[((size_t)b * QQ + qq) * DIMN + m * DHD + d] = og / lg;
  }
}

// ---------- K7: tiled epilogue: 16 q / block, 256 threads ----------
// proj + skip + preLN + MLP(GELU) + postLN + transposed store, all through LDS.
#define EQ 16
#define EPAD 4
__global__ __launch_bounds__(256)
void k_epi2(const float* __restrict__ a, const float* __restrict__ x,
            const float* __restrict__ Wproj, const float* __restrict__ bproj,
            const float* __restrict__ preg, const float* __restrict__ preb,
            const float* __restrict__ W1, const float* __restrict__ b1,
            const float* __restrict__ W2, const float* __restrict__ b2,
            const float* __restrict__ postg, const float* __restrict__ postb,
            float* __restrict__ out) {
  __shared__ float sa[EQ][DIMN + EPAD];    // a tile, later final-output transpose buffer
  __shared__ float sx[EQ][DIMN + EPAD];    // x tile, later reduction scratch
  __shared__ float sln[EQ][DIMN + EPAD];   // preLN result
  __shared__ float sh[EQ][2 * DIMN];       // MLP hidden
  __shared__ float stats[EQ][2];
  int q0 = blockIdx.x * EQ;
  int b  = blockIdx.y;
  int t  = threadIdx.x;
  int d  = t & 127, rg = t >> 7;

  // stage a (row-major, coalesced) and x (transposed, 64B segments per d)
  #pragma unroll
  for (int i = 0; i < 8; ++i) {
    int e = i * 256 + t;
    int q = e >> 7, dd = e & 127;
    int qq = q0 + q;
    sa[q][dd] = (qq < QQ) ? a[((size_t)b * QQ + qq) * DIMN + dd] : 0.f;
  }
  #pragma unroll
  for (int i = 0; i < 8; ++i) {
    int e = i * 256 + t;
    int dd = e >> 4, qi = e & 15;
    int qq = q0 + qi;
    sx[qi][dd] = (qq < QQ) ? x[((size_t)b * DIMN + dd) * QQ + qq] : 0.f;
  }
  __syncthreads();

  // proj: thread (d, rg) computes z for 8 rows, reusing its Wproj row
  float z[8];
  {
    const float4* Wp = (const float4*)Wproj + d * 32;
    float bp = bproj[d];
    #pragma unroll
    for (int r = 0; r < 8; ++r) z[r] = bp + sx[rg * 8 + r][d];
    for (int c4 = 0; c4 < 32; ++c4) {
      float4 w = Wp[c4];
      #pragma unroll
      for (int r = 0; r < 8; ++r) {
        float4 av = *(const float4*)&sa[rg * 8 + r][c4 * 4];
        z[r] += w.x * av.x + w.y * av.y + w.z * av.z + w.w * av.w;
      }
    }
  }
  // preLN stats (reduce over d per row) via sx scratch
  __syncthreads();
  #pragma unroll
  for (int r = 0; r < 8; ++r) sx[rg * 8 + r][d] = z[r];
  __syncthreads();
  {
    int rt = t >> 4, lane = t & 15;
    float s = 0.f, s2 = 0.f;
    #pragma unroll
    for (int j = 0; j < 8; ++j) { float v = sx[rt][lane + 16 * j]; s += v; s2 += v * v; }
    #pragma unroll
    for (int msk = 1; msk < 16; msk <<= 1) { s += __shfl_xor(s, msk, 16); s2 += __shfl_xor(s2, msk, 16); }
    if (lane == 0) { stats[rt][0] = s * (1.f / 128.f); stats[rt][1] = s2 * (1.f / 128.f); }
  }
  __syncthreads();
  float ln1[8];
  {
    float pg = preg[d], pb = preb[d];
    #pragma unroll
    for (int r = 0; r < 8; ++r) {
      int rr = rg * 8 + r;
      float mu  = stats[rr][0];
      float var = fmaxf(stats[rr][1] - mu * mu, 0.f);
      ln1[r] = (z[r] - mu) * rsqrtf(var + 1e-5f) * pg + pb;
      sln[rr][d] = ln1[r];
    }
  }
  __syncthreads();
  // MLP1: thread = hidden column (0..255), 16 rows each
  {
    const float4* W1p = (const float4*)W1 + t * 32;
    float hb = b1[t];
    float h[16];
    #pragma unroll
    for (int r = 0; r < 16; ++r) h[r] = hb;
    for (int c4 = 0; c4 < 32; ++c4) {
      float4 w = W1p[c4];
      #pragma unroll
      for (int r = 0; r < 16; ++r) {
        float4 lv = *(const float4*)&sln[r][c4 * 4];
        h[r] += w.x * lv.x + w.y * lv.y + w.z * lv.z + w.w * lv.w;
      }
    }
    #pragma unroll
    for (int r = 0; r < 16; ++r) {
      float hv = h[r];
      sh[r][t] = 0.5f * hv * (1.f + erff(hv * 0.70710678118f));
    }
  }
  __syncthreads();
  // MLP2: back on (d, rg), 8 rows, W2 row reused 8x
  float o[8];
  {
    const float4* W2p = (const float4*)W2 + d * 64;
    float b2v = b2[d];
    #pragma unroll
    for (int r = 0; r < 8; ++r) o[r] = ln1[r] + b2v;
    for (int c4 = 0; c4 < 64; ++c4) {
      float4 w = W2p[c4];
      #pragma unroll
      for (int r = 0; r < 8; ++r) {
        float4 hv = *(const float4*)&sh[rg * 8 + r][c4 * 4];
        o[r] += w.x * hv.x + w.y * hv.y + w.z * hv.z + w.w * hv.w;
      }
    }
  }
  // postLN stats via sx scratch
  __syncthreads();
  #pragma unroll
  for (int r = 0; r < 8; ++r) sx[rg * 8 + r][d] = o[r];
  __syncthreads();
  {
    int rt = t >> 4, lane = t & 15;
    float s = 0.f, s2 = 0.f;
    #pragma unroll
    for (int j = 0; j < 8; ++j) { float v = sx[rt][lane + 16 * j]; s += v; s2 += v * v; }
    #pragma unroll
    for (int msk = 1; msk < 16; msk <<= 1) { s += __shfl_xor(s, msk, 16); s2 += __shfl_xor(s2, msk, 16); }
    if (lane == 0) { stats[rt][0] = s * (1.f / 128.f); stats[rt][1] = s2 * (1.f / 128.f); }
  }
  __syncthreads();
  {
    float pg = postg[d], pb = postb[d];
    #pragma unroll
    for (int r = 0; r < 8; ++r) {
      int rr = rg * 8 + r;
      float mu  = stats[rr][0];
      float var = fmaxf(stats[rr][1] - mu * mu, 0.f);
      sa[rr][d] = (o[r] - mu) * rsqrtf(var + 1e-5f) * pg + pb;
    }
  }
  __syncthreads();
  // transposed store: 64B-contiguous q segments per d
  #pragma unroll
  for (int i = 0; i < 8; ++i) {
    int e = i * 256 + t;
    int dd = e >> 4, qi = e & 15;
    int qq = q0 + qi;
    if (qq < QQ) out[((size_t)b * DIMN + dd) * QQ + qq] = sa[qi][dd];
  }
}

// ---------- launch ----------
extern "C" void kernel_launch(void* const* d_in, const int* in_sizes, int n_in,
                              void* d_out, int out_size, void* d_ws, size_t ws_size,
                              hipStream_t stream) {
  const float* x        = (const float*)d_in[0];
  const float* feature  = (const float*)d_in[1];
  const float* I_inv    = (const float*)d_in[2];
  const float* E_inv    = (const float*)d_in[3];
  const float* bev_grid = (const float*)d_in[4];
  const float* plane    = (const float*)d_in[5];
  const float* W_cam    = (const float*)d_in[6];
  const float* W_img    = (const float*)d_in[7];
  const float* W_bev    = (const float*)d_in[8];
  const float* b_bev    = (const float*)d_in[9];
  const float* fp_g = (const float*)d_in[10];
  const float* fp_b = (const float*)d_in[11];
  const float* fp_m = (const float*)d_in[12];
  const float* fp_v = (const float*)d_in[13];
  const float* fl_g = (const float*)d_in[14];
  const float* fl_b = (const float*)d_in[15];
  const float* fl_m = (const float*)d_in[16];
  const float* fl_v = (const float*)d_in[17];
  const float* W_fproj = (const float*)d_in[18];
  const float* W_flin  = (const float*)d_in[19];
  const float* q_ln_g = (const float*)d_in[20];
  const float* q_ln_b = (const float*)d_in[21];
  const float* Wq = (const float*)d_in[22];
  const float* bq = (const float*)d_in[23];
  const float* k_ln_g = (const float*)d_in[24];
  const float* k_ln_b = (const float*)d_in[25];
  const float* Wk = (const float*)d_in[26];
  const float* bk = (const float*)d_in[27];
  const float* v_ln_g = (const float*)d_in[28];
  const float* v_ln_b = (const float*)d_in[29];
  const float* Wv = (const float*)d_in[30];
  const float* bv = (const float*)d_in[31];
  const float* Wproj = (const float*)d_in[32];
  const float* bproj = (const float*)d_in[33];
  const float* pre_g = (const float*)d_in[34];
  const float* pre_b = (const float*)d_in[35];
  const float* W1 = (const float*)d_in[36];
  const float* b1 = (const float*)d_in[37];
  const float* W2 = (const float*)d_in[38];
  const float* b2 = (const float*)d_in[39];
  const float* post_g = (const float*)d_in[40];
  const float* post_b = (const float*)d_in[41];

  float* ws    = (float*)d_ws;
  float* ce    = ws;                       // 2048
  float* keyb  = ce + 2048;                // 2,580,480
  float* valb  = keyb + 2580480;           // 2,580,480
  float* query = valb + 2580480;           // 3,840,000
  float* aout  = query + 3840000;          // 640,000
  unsigned short* qhB = (unsigned short*)(aout + 640000);  // 3,840,000 u16
  unsigned short* vhB = qhB + 3840000;                     // 2,580,480 u16 (tail OOB spills into khB: safe)
  unsigned short* khB = vhB + 2580480;                     // 2,580,480 u16

  k_cembed<<<12, 128, 0, stream>>>(W_cam, E_inv, ce);
  k_img<<<dim3(KK, 12), 128, 0, stream>>>(I_inv, E_inv, plane, W_img, ce, keyb);
  k_query<<<dim3(QQ, 12), 128, 0, stream>>>(bev_grid, W_bev, b_bev, ce, x, query);
  k_featconv<<<dim3(KK / TP, 12), 256, 0, stream>>>(feature,
      fp_g, fp_b, fp_m, fp_v, fl_g, fl_b, fl_m, fl_v, W_fproj, W_flin, keyb, valb);
  k_lnproj_bf<0><<<(12 * QQ) / ROWS, 128, 0, stream>>>(query, q_ln_g, q_ln_b, Wq, bq, qhB, SCALE);
  k_lnproj_bf<0><<<(12 * KK) / ROWS, 128, 0, stream>>>(keyb, k_ln_g, k_ln_b, Wk, bk, khB, 1.0f);
  k_lnproj_bf<1><<<(12 * KK) / ROWS, 128, 0, stream>>>(valb, v_ln_g, v_ln_b, Wv, bv, vhB, 1.0f);
  k_attn_mfma<<<dim3((QQ + 15) / 16, NHEAD, NB), 512, 0, stream>>>(qhB, khB, vhB, aout);
  k_epi2<<<dim3((QQ + EQ - 1) / EQ, NB), 256, 0, stream>>>(aout, x, Wproj, bproj,
      pre_g, pre_b, W1, b1, W2, b2, post_g, post_b, (float*)d_out);
}